// Round 7
// baseline (112.810 us; speedup 1.0000x reference)
//
#include <hip/hip_runtime.h>
#include <hip/hip_bf16.h>

#define B_   32
#define N_   2048
#define VD_  512
#define AD_  128
#define SD_  128
#define TM   32
#define THREADS 256

typedef __attribute__((ext_vector_type(8))) short short8;
typedef __attribute__((ext_vector_type(4))) float f32x4;

// ws layout (ushort element offsets) for fragment-packed bf16 weights.
// Packing: for W[C][K], frag (n,kc,l,e): dst[((n*(K/32)+kc)*64+l)*8+e] = W[n*16+(l&15)][kc*32+(l>>4)*8+e]
#define WOFF_VFC 0        // C=128,K=512: 65536
#define WOFF_AFC 65536    // C=128,K=128: 16384
#define WOFF_AM  81920    // C=128,K=128: 16384
#define WOFF_V   98304    // C=64, K=128: 8192
#define WOFF_U   106496   // C=64, K=128: 8192
#define WTOT     114688   // ushorts = 229376 bytes; zpart (bf16) follows

__device__ __forceinline__ float sigmoidf_(float x) { return 1.0f / (1.0f + __expf(-x)); }

__device__ __forceinline__ ushort f2bf(float x) {   // RNE
    union { float f; unsigned int i; } v; v.f = x;
    unsigned int r = v.i + 0x7FFFu + ((v.i >> 16) & 1u);
    return (ushort)(r >> 16);
}
__device__ __forceinline__ float bf2f(ushort u) {
    union { unsigned int i; float f; } v; v.i = ((unsigned int)u) << 16; return v.f;
}
// Xbuf swizzle: ushort [R][128], XOR on 16B chunks
__device__ __forceinline__ int swz(int row, int k, int ldk) {
    return row * ldk + (k ^ ((row & 7) << 3));
}
// 8x f32 -> 8x bf16 via packed convert (RNE)
__device__ __forceinline__ short8 pack8(float4 x, float4 y) {
    union { unsigned int u[4]; short8 s; } o;
    asm("v_cvt_pk_bf16_f32 %0, %1, %2" : "=v"(o.u[0]) : "v"(x.x), "v"(x.y));
    asm("v_cvt_pk_bf16_f32 %0, %1, %2" : "=v"(o.u[1]) : "v"(x.z), "v"(x.w));
    asm("v_cvt_pk_bf16_f32 %0, %1, %2" : "=v"(o.u[2]) : "v"(y.x), "v"(y.y));
    asm("v_cvt_pk_bf16_f32 %0, %1, %2" : "=v"(o.u[3]) : "v"(y.z), "v"(y.w));
    return o.s;
}

// ---- weight pre-conversion + fragment packing ----
__global__ __launch_bounds__(256)
void cvt_weights(const float* __restrict__ vfc, const float* __restrict__ afc,
                 const float* __restrict__ am,  const float* __restrict__ Vw,
                 const float* __restrict__ Uw,  ushort* __restrict__ dst)
{
    int f = blockIdx.x * 256 + threadIdx.x;
    if (f >= WTOT / 8) return;
    int e0 = f * 8;
    const float* src; int base, K;
    if      (e0 < WOFF_AFC) { src = vfc; base = WOFF_VFC; K = 512; }
    else if (e0 < WOFF_AM)  { src = afc; base = WOFF_AFC; K = 128; }
    else if (e0 < WOFF_V)   { src = am;  base = WOFF_AM;  K = 128; }
    else if (e0 < WOFF_U)   { src = Vw;  base = WOFF_V;   K = 128; }
    else                    { src = Uw;  base = WOFF_U;   K = 128; }
    int lf = f - base / 8;
    int l = lf & 63, rem = lf >> 6;
    int NK = K / 32;
    int kc = rem % NK, n = rem / NK;
    int tc = l & 15, g4 = l >> 4;
    const float* sp = src + (size_t)(n * 16 + tc) * K + kc * 32 + g4 * 8;
    float4 x = ((const float4*)sp)[0], y = ((const float4*)sp)[1];
    short8 o = pack8(x, y);
    *(short8*)(dst + e0) = o;
}

// GEMM over a 32-row token tile: A direct from global f32 (cvt in-reg),
// B fragment-packed global bf16. Wave wc owns cols 32wc..32wc+31 (n-tiles 2wc,2wc+1).
// No LDS, no barriers; depth-1 reg prefetch; TLP (32 waves/CU) hides latency.
template<int K>
__device__ __forceinline__ void gemm_gp2(const float* __restrict__ A,     // tile base, ld=K
                                         const ushort* __restrict__ Bp,
                                         int wc, int t16, int g4, int lane,
                                         f32x4 (&acc)[2][2])
{
    constexpr int NK = K / 32;
    const float* a0p = A + (size_t)t16 * K + g4 * 8;
    const float* a1p = A + (size_t)(t16 + 16) * K + g4 * 8;
    const ushort* bp = Bp + (size_t)(2 * wc) * NK * 512 + lane * 8;

    float4 pa[4]; short8 pb[2];
    pa[0] = ((const float4*)a0p)[0]; pa[1] = ((const float4*)a0p)[1];
    pa[2] = ((const float4*)a1p)[0]; pa[3] = ((const float4*)a1p)[1];
    pb[0] = *(const short8*)(bp);
    pb[1] = *(const short8*)(bp + (size_t)NK * 512);

    #pragma unroll
    for (int kc = 0; kc < NK; ++kc) {
        short8 a0 = pack8(pa[0], pa[1]);
        short8 a1 = pack8(pa[2], pa[3]);
        short8 b0 = pb[0], b1 = pb[1];
        if (kc + 1 < NK) {
            const float* na0 = a0p + (kc + 1) * 32;
            const float* na1 = a1p + (kc + 1) * 32;
            pa[0] = ((const float4*)na0)[0]; pa[1] = ((const float4*)na0)[1];
            pa[2] = ((const float4*)na1)[0]; pa[3] = ((const float4*)na1)[1];
            pb[0] = *(const short8*)(bp + (size_t)(kc + 1) * 512);
            pb[1] = *(const short8*)(bp + (size_t)(kc + 1) * 512 + (size_t)NK * 512);
        }
        acc[0][0] = __builtin_amdgcn_mfma_f32_16x16x32_bf16(a0, b0, acc[0][0], 0, 0, 0);
        acc[1][0] = __builtin_amdgcn_mfma_f32_16x16x32_bf16(a1, b0, acc[1][0], 0, 0, 0);
        acc[0][1] = __builtin_amdgcn_mfma_f32_16x16x32_bf16(a0, b1, acc[0][1], 0, 0, 0);
        acc[1][1] = __builtin_amdgcn_mfma_f32_16x16x32_bf16(a1, b1, acc[1][1], 0, 0, 0);
    }
}

// GEMM with A from swizzled LDS bf16 (Xbuf [32][128]), B fragment-packed global.
template<int K>
__device__ __forceinline__ void gemm_lp2(const ushort* __restrict__ Ab,
                                         const ushort* __restrict__ Bp,
                                         int wc, int t16, int g4, int lane,
                                         f32x4 (&acc)[2][2])
{
    constexpr int NK = K / 32;
    const ushort* bp = Bp + (size_t)(2 * wc) * NK * 512 + lane * 8;
    short8 pb[2];
    pb[0] = *(const short8*)(bp);
    pb[1] = *(const short8*)(bp + (size_t)NK * 512);

    #pragma unroll
    for (int kc = 0; kc < NK; ++kc) {
        int k = kc * 32 + g4 * 8;
        short8 a0 = *(const short8*)&Ab[swz(t16,      k, 128)];
        short8 a1 = *(const short8*)&Ab[swz(t16 + 16, k, 128)];
        short8 b0 = pb[0], b1 = pb[1];
        if (kc + 1 < NK) {
            pb[0] = *(const short8*)(bp + (size_t)(kc + 1) * 512);
            pb[1] = *(const short8*)(bp + (size_t)(kc + 1) * 512 + (size_t)NK * 512);
        }
        acc[0][0] = __builtin_amdgcn_mfma_f32_16x16x32_bf16(a0, b0, acc[0][0], 0, 0, 0);
        acc[1][0] = __builtin_amdgcn_mfma_f32_16x16x32_bf16(a1, b0, acc[1][0], 0, 0, 0);
        acc[0][1] = __builtin_amdgcn_mfma_f32_16x16x32_bf16(a0, b1, acc[0][1], 0, 0, 0);
        acc[1][1] = __builtin_amdgcn_mfma_f32_16x16x32_bf16(a1, b1, acc[1][1], 0, 0, 0);
    }
}

// Grid: 32 b x 64 tiles = 2048 blocks, 256 threads (4 waves).
// LDS ~10KB, 64 VGPR -> 8 blocks/CU = 32 waves/CU (100% occupancy), grid = 1 full round.
__global__ __launch_bounds__(THREADS, 8)
void fused_mil(const float* __restrict__ vfeat, const float* __restrict__ afeat,
               const ushort* __restrict__ wsW,
               const float* __restrict__ afc_b, const float* __restrict__ am_b,
               const float* __restrict__ vfc_b,
               const float* __restrict__ V_b,   const float* __restrict__ U_b,
               const float* __restrict__ W_w,   const float* __restrict__ W_b,
               float* __restrict__ s_out, ushort* __restrict__ zpart)
{
    __shared__ __align__(16) ushort Xbuf[TM * 128];   // ax -> gate -> ffeat (aliased), 8KB
    __shared__ float sP[4][TM];                       // per-wave score partials
    __shared__ float sS[TM];
    __shared__ float zq[2][128];

    const int tid  = threadIdx.x;
    const int bx   = blockIdx.x;
    const int b    = bx >> 6;
    const int tok0 = (bx & 63) * TM;
    const int wid  = tid >> 6;      // = wc, 0..3
    const int lane = tid & 63;
    const int t16  = lane & 15;
    const int g4   = lane >> 4;
    const int wc   = wid;

    const float* afeat_t = afeat + ((size_t)b * N_ + tok0) * AD_;
    const float* vfeat_t = vfeat + ((size_t)b * N_ + tok0) * VD_;

    f32x4 acc[2][2];

    // ---- Phase A: ax = relu(afeat @ afc_w^T + afc_b) -> Xbuf ----
    #pragma unroll
    for (int m = 0; m < 2; ++m)
        #pragma unroll
        for (int n = 0; n < 2; ++n) acc[m][n] = (f32x4)0.0f;
    gemm_gp2<AD_>(afeat_t, wsW + WOFF_AFC, wc, t16, g4, lane, acc);
    #pragma unroll
    for (int n = 0; n < 2; ++n) {
        int c = 32 * wc + 16 * n + t16;
        float bias = afc_b[c];
        #pragma unroll
        for (int m = 0; m < 2; ++m)
            #pragma unroll
            for (int r = 0; r < 4; ++r) {
                int row = 16 * m + 4 * g4 + r;
                Xbuf[swz(row, c, 128)] = f2bf(fmaxf(acc[m][n][r] + bias, 0.0f));
            }
    }
    __syncthreads();                                   // ax visible to all waves

    // ---- Phase B: gate = sigmoid(ax @ am_w^T + am_b), stashed bf16 into Xbuf ----
    #pragma unroll
    for (int m = 0; m < 2; ++m)
        #pragma unroll
        for (int n = 0; n < 2; ++n) acc[m][n] = (f32x4)0.0f;
    gemm_lp2<SD_>(Xbuf, wsW + WOFF_AM, wc, t16, g4, lane, acc);
    __syncthreads();                                   // everyone done reading ax
    #pragma unroll
    for (int n = 0; n < 2; ++n) {
        int c = 32 * wc + 16 * n + t16;
        float bias = am_b[c];
        #pragma unroll
        for (int m = 0; m < 2; ++m)
            #pragma unroll
            for (int r = 0; r < 4; ++r) {
                int row = 16 * m + 4 * g4 + r;
                Xbuf[swz(row, c, 128)] = f2bf(sigmoidf_(acc[m][n][r] + bias));
            }
    }
    // no barrier: phase C touches no LDS; gate cells are thread-private

    // ---- Phase C: vo1 = vfeat @ vfc_w^T (K=512, barrier-free register stream) ----
    #pragma unroll
    for (int m = 0; m < 2; ++m)
        #pragma unroll
        for (int n = 0; n < 2; ++n) acc[m][n] = (f32x4)0.0f;
    gemm_gp2<VD_>(vfeat_t, wsW + WOFF_VFC, wc, t16, g4, lane, acc);

    // epilogue: ffeat = relu(vo1+b) * (1 + gate) -> Xbuf (thread-private cells)
    #pragma unroll
    for (int n = 0; n < 2; ++n) {
        int c = 32 * wc + 16 * n + t16;
        float vb = vfc_b[c];
        #pragma unroll
        for (int m = 0; m < 2; ++m)
            #pragma unroll
            for (int r = 0; r < 4; ++r) {
                int row = 16 * m + 4 * g4 + r;
                float g   = bf2f(Xbuf[swz(row, c, 128)]);
                float vo1 = fmaxf(acc[m][n][r] + vb, 0.0f);
                Xbuf[swz(row, c, 128)] = f2bf(vo1 * (1.0f + g));
            }
    }
    __syncthreads();

    // ---- Phase E: v/u heads. Wave wc: V-tile wc (n=0) and U-tile wc (n=1),
    //      both at h = 16*wc + t16. ----
    #pragma unroll
    for (int m = 0; m < 2; ++m)
        #pragma unroll
        for (int n = 0; n < 2; ++n) acc[m][n] = (f32x4)0.0f;
    {
        const ushort* Vp = wsW + WOFF_V + (size_t)wc * 4 * 512 + lane * 8;
        const ushort* Up = wsW + WOFF_U + (size_t)wc * 4 * 512 + lane * 8;
        short8 pbv = *(const short8*)Vp;
        short8 pbu = *(const short8*)Up;
        #pragma unroll
        for (int kc = 0; kc < 4; ++kc) {
            int k = kc * 32 + g4 * 8;
            short8 a0 = *(const short8*)&Xbuf[swz(t16,      k, 128)];
            short8 a1 = *(const short8*)&Xbuf[swz(t16 + 16, k, 128)];
            short8 b0 = pbv, b1 = pbu;
            if (kc < 3) {
                pbv = *(const short8*)(Vp + (size_t)(kc + 1) * 512);
                pbu = *(const short8*)(Up + (size_t)(kc + 1) * 512);
            }
            acc[0][0] = __builtin_amdgcn_mfma_f32_16x16x32_bf16(a0, b0, acc[0][0], 0, 0, 0);
            acc[1][0] = __builtin_amdgcn_mfma_f32_16x16x32_bf16(a1, b0, acc[1][0], 0, 0, 0);
            acc[0][1] = __builtin_amdgcn_mfma_f32_16x16x32_bf16(a0, b1, acc[0][1], 0, 0, 0);
            acc[1][1] = __builtin_amdgcn_mfma_f32_16x16x32_bf16(a1, b1, acc[1][1], 0, 0, 0);
        }
    }

    // ---- score s = sum_h relu(v)*sigmoid(u)*W_w + W_b ----
    {
        int h = 16 * wc + t16;
        float vb = V_b[h], ub = U_b[h], ww = W_w[h];
        #pragma unroll
        for (int m = 0; m < 2; ++m)
            #pragma unroll
            for (int r = 0; r < 4; ++r) {
                float vv = fmaxf(acc[m][0][r] + vb, 0.0f);
                float uu = sigmoidf_(acc[m][1][r] + ub);
                float p = vv * uu * ww;
                p += __shfl_xor(p, 1);
                p += __shfl_xor(p, 2);
                p += __shfl_xor(p, 4);
                p += __shfl_xor(p, 8);
                if (t16 == 0) sP[wc][16 * m + 4 * g4 + r] = p;
            }
    }
    __syncthreads();
    if (tid < TM) {
        float s = sP[0][tid] + sP[1][tid] + sP[2][tid] + sP[3][tid] + W_b[0];
        sS[tid] = s;
        s_out[(size_t)b * N_ + tok0 + tid] = s;
    }
    __syncthreads();

    // ---- Phase F: zpart[k] = sum_t s[t] * ffeat[t][k]  (bf16 partials) ----
    {
        int k = tid & 127, q = tid >> 7;     // q in {0,1}: rows 16q..16q+15
        float z = 0.0f;
        #pragma unroll
        for (int t = 0; t < 16; ++t) {
            int row = q * 16 + t;
            z = fmaf(sS[row], bf2f(Xbuf[swz(row, k, 128)]), z);
        }
        zq[q][k] = z;
    }
    __syncthreads();
    if (tid < 128)
        zpart[(size_t)bx * 128 + tid] = f2bf(zq[0][tid] + zq[1][tid]);
}

// Grid: 32 blocks, 128 threads.
__global__ __launch_bounds__(128)
void reduce_logits(const ushort* __restrict__ zpart,
                   const float* __restrict__ cls_w, const float* __restrict__ cls_b,
                   float* __restrict__ out)
{
    __shared__ float sZ[128];
    int b = blockIdx.x, k = threadIdx.x;
    float z = 0.0f;
    #pragma unroll
    for (int t = 0; t < 64; ++t) z += bf2f(zpart[(size_t)(b * 64 + t) * 128 + k]);
    sZ[k] = z;
    __syncthreads();
    if (k < 2) {
        float acc = cls_b[k];
        for (int i = 0; i < 128; ++i) acc = fmaf(sZ[i], cls_w[k * 128 + i], acc);
        out[(size_t)B_ * N_ + b * 2 + k] = acc;
    }
}

extern "C" void kernel_launch(void* const* d_in, const int* in_sizes, int n_in,
                              void* d_out, int out_size, void* d_ws, size_t ws_size,
                              hipStream_t stream) {
    const float* vfeat = (const float*)d_in[0];
    const float* afeat = (const float*)d_in[1];
    const float* vfc_w = (const float*)d_in[2];
    const float* vfc_b = (const float*)d_in[3];
    const float* afc_w = (const float*)d_in[4];
    const float* afc_b = (const float*)d_in[5];
    const float* am_w  = (const float*)d_in[6];
    const float* am_b  = (const float*)d_in[7];
    const float* U_w   = (const float*)d_in[8];
    const float* U_b   = (const float*)d_in[9];
    const float* V_w   = (const float*)d_in[10];
    const float* V_b   = (const float*)d_in[11];
    const float* W_w   = (const float*)d_in[12];
    const float* W_b   = (const float*)d_in[13];
    const float* cls_w = (const float*)d_in[14];
    const float* cls_b = (const float*)d_in[15];

    float* out    = (float*)d_out;
    ushort* wsW   = (ushort*)d_ws;                             // 229376 B packed bf16 weights
    ushort* zpart = (ushort*)((char*)d_ws + (size_t)WTOT * 2); // 2048*128*2 = 512 KB

    cvt_weights<<<dim3((WTOT / 8 + 255) / 256), dim3(256), 0, stream>>>(vfc_w, afc_w, am_w, V_w, U_w, wsW);
    fused_mil<<<dim3(B_ * 64), dim3(THREADS), 0, stream>>>(
        vfeat, afeat, wsW, afc_b, am_b, vfc_b, V_b, U_b, W_w, W_b, out, zpart);
    reduce_logits<<<dim3(B_), dim3(128), 0, stream>>>(zpart, cls_w, cls_b, out);
}

// Round 8
// 91.175 us; speedup vs baseline: 1.2373x; 1.2373x over previous
//
#include <hip/hip_runtime.h>
#include <hip/hip_bf16.h>

#define B_   32
#define N_   2048
#define VD_  512
#define AD_  128
#define SD_  128
#define THREADS 256

typedef __attribute__((ext_vector_type(8))) short short8;
typedef __attribute__((ext_vector_type(4))) float f32x4;

// ws layout (ushort element offsets) for fragment-packed bf16 weights.
// Packing: for W[C][K], frag (n,kc,l,e): dst[((n*(K/32)+kc)*64+l)*8+e] = W[n*16+(l&15)][kc*32+(l>>4)*8+e]
#define WOFF_VFC 0        // C=128,K=512: 65536
#define WOFF_AFC 65536    // C=128,K=128: 16384
#define WOFF_AM  81920    // C=128,K=128: 16384
#define WOFF_V   98304    // C=64, K=128: 8192  (U follows contiguously -> V|U = 8 n-tiles)
#define WOFF_U   106496   // C=64, K=128: 8192
#define WTOT     114688   // ushorts = 229376 bytes; zpart follows

__device__ __forceinline__ float sigmoidf_(float x) { return 1.0f / (1.0f + __expf(-x)); }

__device__ __forceinline__ ushort f2bf(float x) {   // RNE
    union { float f; unsigned int i; } v; v.f = x;
    unsigned int r = v.i + 0x7FFFu + ((v.i >> 16) & 1u);
    return (ushort)(r >> 16);
}
__device__ __forceinline__ float bf2f(ushort u) {
    union { unsigned int i; float f; } v; v.i = ((unsigned int)u) << 16; return v.f;
}
// swizzle for ushort [16][128] LDS slice, XOR on 16B chunks
__device__ __forceinline__ int swz(int row, int k, int ldk) {
    return row * ldk + (k ^ ((row & 7) << 3));
}
// 8x f32 -> 8x bf16 via packed convert (RNE)
__device__ __forceinline__ short8 pack8(float4 x, float4 y) {
    union { unsigned int u[4]; short8 s; } o;
    asm("v_cvt_pk_bf16_f32 %0, %1, %2" : "=v"(o.u[0]) : "v"(x.x), "v"(x.y));
    asm("v_cvt_pk_bf16_f32 %0, %1, %2" : "=v"(o.u[1]) : "v"(x.z), "v"(x.w));
    asm("v_cvt_pk_bf16_f32 %0, %1, %2" : "=v"(o.u[2]) : "v"(y.x), "v"(y.y));
    asm("v_cvt_pk_bf16_f32 %0, %1, %2" : "=v"(o.u[3]) : "v"(y.z), "v"(y.w));
    return o.s;
}

// ---- weight pre-conversion + fragment packing ----
__global__ __launch_bounds__(256)
void cvt_weights(const float* __restrict__ vfc, const float* __restrict__ afc,
                 const float* __restrict__ am,  const float* __restrict__ Vw,
                 const float* __restrict__ Uw,  ushort* __restrict__ dst)
{
    int f = blockIdx.x * 256 + threadIdx.x;
    if (f >= WTOT / 8) return;
    int e0 = f * 8;
    const float* src; int base, K;
    if      (e0 < WOFF_AFC) { src = vfc; base = WOFF_VFC; K = 512; }
    else if (e0 < WOFF_AM)  { src = afc; base = WOFF_AFC; K = 128; }
    else if (e0 < WOFF_V)   { src = am;  base = WOFF_AM;  K = 128; }
    else if (e0 < WOFF_U)   { src = Vw;  base = WOFF_V;   K = 128; }
    else                    { src = Uw;  base = WOFF_U;   K = 128; }
    int lf = f - base / 8;
    int l = lf & 63, rem = lf >> 6;
    int NK = K / 32;
    int kc = rem % NK, n = rem / NK;
    int tc = l & 15, g4 = l >> 4;
    const float* sp = src + (size_t)(n * 16 + tc) * K + kc * 32 + g4 * 8;
    float4 x = ((const float4*)sp)[0], y = ((const float4*)sp)[1];
    short8 o = pack8(x, y);
    *(short8*)(dst + e0) = o;
}

// Wave-autonomous GEMM over a 16-token tile: A streamed from global f32
// (one row per lane: row = t16), B fragment-packed bf16 (L2-hot).
// acc[n], n=0..7 covers all 128 output cols. Depth-RING A-prefetch ring.
template<int NK, int RING>
__device__ __forceinline__ void gemm_stream(const float* __restrict__ aRow,  // + t16*K + g4*8
                                            const ushort* __restrict__ bp,   // + lane*8
                                            f32x4 (&acc)[8])
{
    float4 pa[RING][2];
    #pragma unroll
    for (int i = 0; i < RING; ++i) {
        pa[i][0] = *(const float4*)(aRow + i * 32);
        pa[i][1] = *(const float4*)(aRow + i * 32 + 4);
    }
    #pragma unroll
    for (int kc = 0; kc < NK; ++kc) {
        short8 a = pack8(pa[kc % RING][0], pa[kc % RING][1]);
        if (kc + RING < NK) {
            pa[kc % RING][0] = *(const float4*)(aRow + (kc + RING) * 32);
            pa[kc % RING][1] = *(const float4*)(aRow + (kc + RING) * 32 + 4);
        }
        #pragma unroll
        for (int n = 0; n < 8; ++n) {
            short8 b = *(const short8*)(bp + ((size_t)n * NK + kc) * 512);
            acc[n] = __builtin_amdgcn_mfma_f32_16x16x32_bf16(a, b, acc[n], 0, 0, 0);
        }
    }
}

// Wave-autonomous GEMM with A from the wave's private LDS slice (bf16, swizzled).
template<int NK>
__device__ __forceinline__ void gemm_lds(const ushort* __restrict__ Xw, int t16, int g4,
                                         const ushort* __restrict__ bp,   // + lane*8
                                         f32x4 (&acc)[8])
{
    #pragma unroll
    for (int kc = 0; kc < NK; ++kc) {
        short8 a = *(const short8*)&Xw[swz(t16, kc * 32 + g4 * 8, 128)];
        #pragma unroll
        for (int n = 0; n < 8; ++n) {
            short8 b = *(const short8*)(bp + ((size_t)n * NK + kc) * 512);
            acc[n] = __builtin_amdgcn_mfma_f32_16x16x32_bf16(a, b, acc[n], 0, 0, 0);
        }
    }
}

// Grid: 32 b x 32 = 1024 blocks, 256 threads (4 waves, each owning 16 tokens).
// Zero barriers until the final zpart reduce. LDS 34.5KB; VGPR cap 128 (4 blk/CU).
__global__ __launch_bounds__(THREADS, 4)
void fused_mil(const float* __restrict__ vfeat, const float* __restrict__ afeat,
               const ushort* __restrict__ wsW,
               const float* __restrict__ afc_b, const float* __restrict__ am_b,
               const float* __restrict__ vfc_b,
               const float* __restrict__ V_b,   const float* __restrict__ U_b,
               const float* __restrict__ W_w,   const float* __restrict__ W_b,
               float* __restrict__ s_out, float* __restrict__ zpart)
{
    __shared__ __align__(16) ushort Xbuf[4][16 * 128];   // per-wave: ax -> ffeat
    __shared__ __align__(16) ushort Gbuf[4][16 * 128];   // per-wave: gate
    __shared__ float zq[4][128];

    const int tid  = threadIdx.x;
    const int bx   = blockIdx.x;
    const int b    = bx >> 5;
    const int wid  = tid >> 6;
    const int lane = tid & 63;
    const int t16  = lane & 15;
    const int g4   = lane >> 4;
    const int tok0 = (bx & 31) * 64 + wid * 16;

    ushort* Xw = Xbuf[wid];
    ushort* Gw = Gbuf[wid];

    const float* afeat_r = afeat + ((size_t)b * N_ + tok0) * AD_ + (size_t)t16 * AD_ + g4 * 8;
    const float* vfeat_r = vfeat + ((size_t)b * N_ + tok0) * VD_ + (size_t)t16 * VD_ + g4 * 8;

    f32x4 acc[8];

    // ---- Phase A: ax = relu(afeat @ afc_w^T + afc_b) -> Xw ----
    #pragma unroll
    for (int n = 0; n < 8; ++n) acc[n] = (f32x4)0.0f;
    gemm_stream<4, 4>(afeat_r, wsW + WOFF_AFC + lane * 8, acc);
    #pragma unroll
    for (int n = 0; n < 8; ++n) {
        int c = 16 * n + t16;
        float bias = afc_b[c];
        #pragma unroll
        for (int r = 0; r < 4; ++r)
            Xw[swz(4 * g4 + r, c, 128)] = f2bf(fmaxf(acc[n][r] + bias, 0.0f));
    }

    // ---- Phase B: gate = sigmoid(ax @ am_w^T + am_b) -> Gw ----
    #pragma unroll
    for (int n = 0; n < 8; ++n) acc[n] = (f32x4)0.0f;
    gemm_lds<4>(Xw, t16, g4, wsW + WOFF_AM + lane * 8, acc);
    #pragma unroll
    for (int n = 0; n < 8; ++n) {
        int c = 16 * n + t16;
        float bias = am_b[c];
        #pragma unroll
        for (int r = 0; r < 4; ++r)
            Gw[swz(4 * g4 + r, c, 128)] = f2bf(sigmoidf_(acc[n][r] + bias));
    }

    // ---- Phase C: vo1 = vfeat @ vfc_w^T (K=512, depth-4 ring, no barriers) ----
    #pragma unroll
    for (int n = 0; n < 8; ++n) acc[n] = (f32x4)0.0f;
    gemm_stream<16, 4>(vfeat_r, wsW + WOFF_VFC + lane * 8, acc);

    // epilogue: ffeat = relu(vo1+b)*(1+gate) -> Xw (bf16) and ff regs (f32)
    float ff[8][4];
    #pragma unroll
    for (int n = 0; n < 8; ++n) {
        int c = 16 * n + t16;
        float vb = vfc_b[c];
        #pragma unroll
        for (int r = 0; r < 4; ++r) {
            float g = bf2f(Gw[swz(4 * g4 + r, c, 128)]);
            float f = fmaxf(acc[n][r] + vb, 0.0f) * (1.0f + g);
            ff[n][r] = f;
            Xw[swz(4 * g4 + r, c, 128)] = f2bf(f);
        }
    }

    // ---- Phase E: v|u heads (V,U packed contiguously -> 8 n-tiles of NK=4) ----
    #pragma unroll
    for (int n = 0; n < 8; ++n) acc[n] = (f32x4)0.0f;
    gemm_lds<4>(Xw, t16, g4, wsW + WOFF_V + lane * 8, acc);

    // ---- score s = sum_h relu(v)*sigmoid(u)*W_w + W_b (in-register) ----
    float s[4];
    {
        float p[4] = {0.0f, 0.0f, 0.0f, 0.0f};
        #pragma unroll
        for (int n = 0; n < 4; ++n) {
            int h = 16 * n + t16;
            float vb = V_b[h], ub = U_b[h], ww = W_w[h];
            #pragma unroll
            for (int r = 0; r < 4; ++r) {
                float vv = fmaxf(acc[n][r] + vb, 0.0f);
                float uu = sigmoidf_(acc[n + 4][r] + ub);
                p[r] = fmaf(vv * uu, ww, p[r]);
            }
        }
        float wb = W_b[0];
        #pragma unroll
        for (int r = 0; r < 4; ++r) {
            p[r] += __shfl_xor(p[r], 1);
            p[r] += __shfl_xor(p[r], 2);
            p[r] += __shfl_xor(p[r], 4);
            p[r] += __shfl_xor(p[r], 8);
            s[r] = p[r] + wb;
        }
        if (t16 == 0) {
            #pragma unroll
            for (int r = 0; r < 4; ++r)
                s_out[(size_t)b * N_ + tok0 + 4 * g4 + r] = s[r];
        }
    }

    // ---- Phase F: z[k] = sum_t s[t]*ffeat[t][k] (registers + shfl) ----
    #pragma unroll
    for (int n = 0; n < 8; ++n) {
        float z = 0.0f;
        #pragma unroll
        for (int r = 0; r < 4; ++r) z = fmaf(s[r], ff[n][r], z);
        z += __shfl_xor(z, 16);
        z += __shfl_xor(z, 32);
        if (g4 == 0) zq[wid][16 * n + t16] = z;
    }
    __syncthreads();
    if (tid < 128)
        zpart[(size_t)bx * 128 + tid] = zq[0][tid] + zq[1][tid] + zq[2][tid] + zq[3][tid];
}

// Grid: 32 blocks, 128 threads.
__global__ __launch_bounds__(128)
void reduce_logits(const float* __restrict__ zpart,
                   const float* __restrict__ cls_w, const float* __restrict__ cls_b,
                   float* __restrict__ out)
{
    __shared__ float sZ[128];
    int b = blockIdx.x, k = threadIdx.x;
    float z = 0.0f;
    #pragma unroll
    for (int t = 0; t < 32; ++t) z += zpart[(size_t)(b * 32 + t) * 128 + k];
    sZ[k] = z;
    __syncthreads();
    if (k < 2) {
        float acc = cls_b[k];
        for (int i = 0; i < 128; ++i) acc = fmaf(sZ[i], cls_w[k * 128 + i], acc);
        out[(size_t)B_ * N_ + b * 2 + k] = acc;
    }
}

extern "C" void kernel_launch(void* const* d_in, const int* in_sizes, int n_in,
                              void* d_out, int out_size, void* d_ws, size_t ws_size,
                              hipStream_t stream) {
    const float* vfeat = (const float*)d_in[0];
    const float* afeat = (const float*)d_in[1];
    const float* vfc_w = (const float*)d_in[2];
    const float* vfc_b = (const float*)d_in[3];
    const float* afc_w = (const float*)d_in[4];
    const float* afc_b = (const float*)d_in[5];
    const float* am_w  = (const float*)d_in[6];
    const float* am_b  = (const float*)d_in[7];
    const float* U_w   = (const float*)d_in[8];
    const float* U_b   = (const float*)d_in[9];
    const float* V_w   = (const float*)d_in[10];
    const float* V_b   = (const float*)d_in[11];
    const float* W_w   = (const float*)d_in[12];
    const float* W_b   = (const float*)d_in[13];
    const float* cls_w = (const float*)d_in[14];
    const float* cls_b = (const float*)d_in[15];

    float* out   = (float*)d_out;
    ushort* wsW  = (ushort*)d_ws;                            // 229376 B packed bf16 weights
    float* zpart = (float*)((char*)d_ws + (size_t)WTOT * 2); // 1024*128*4 = 512 KB

    cvt_weights<<<dim3((WTOT / 8 + 255) / 256), dim3(256), 0, stream>>>(vfc_w, afc_w, am_w, V_w, U_w, wsW);
    fused_mil<<<dim3(B_ * 32), dim3(THREADS), 0, stream>>>(
        vfeat, afeat, wsW, afc_b, am_b, vfc_b, V_b, U_b, W_w, W_b, out, zpart);
    reduce_logits<<<dim3(B_), dim3(128), 0, stream>>>(zpart, cls_w, cls_b, out);
}

// Round 9
// 59.695 us; speedup vs baseline: 1.8898x; 1.5273x over previous
//
#include <hip/hip_runtime.h>
#include <hip/hip_bf16.h>

#define B_   32
#define N_   2048
#define VD_  512
#define AD_  128
#define SD_  128
#define TM   128
#define THREADS 512

typedef __attribute__((ext_vector_type(8))) short short8;
typedef __attribute__((ext_vector_type(4))) float f32x4;

// ws layout (ushort element offsets) for fragment-packed bf16 weights.
// Packing: for W[C][K], frag (n,kc,l,e): dst[((n*(K/32)+kc)*64+l)*8+e] = W[n*16+(l&15)][kc*32+(l>>4)*8+e]
#define WOFF_VFC 0        // C=128,K=512: 65536
#define WOFF_AFC 65536    // C=128,K=128: 16384
#define WOFF_AM  81920    // C=128,K=128: 16384
#define WOFF_V   98304    // C=64, K=128: 8192
#define WOFF_U   106496   // C=64, K=128: 8192
#define WTOT     114688   // ushorts = 229376 bytes; zpart follows

__device__ __forceinline__ float sigmoidf_(float x) { return 1.0f / (1.0f + __expf(-x)); }

__device__ __forceinline__ ushort f2bf(float x) {   // RNE
    union { float f; unsigned int i; } v; v.f = x;
    unsigned int r = v.i + 0x7FFFu + ((v.i >> 16) & 1u);
    return (ushort)(r >> 16);
}
__device__ __forceinline__ float bf2f(ushort u) {
    union { unsigned int i; float f; } v; v.i = ((unsigned int)u) << 16; return v.f;
}
// Xbuf swizzle: ushort [128][128], XOR on 16B chunks
__device__ __forceinline__ int swz(int row, int k, int ldk) {
    return row * ldk + (k ^ ((row & 7) << 3));
}
// Abuf swizzle: f32 [128][32], (row, 16B-chunk c) -> f32 index
__device__ __forceinline__ int fswz(int row, int c) {
    return row * 32 + ((c ^ (row & 7)) << 2);
}
// 8x f32 -> 8x bf16 packed convert (RNE)
__device__ __forceinline__ short8 pack8(float4 x, float4 y) {
    union { unsigned int u[4]; short8 s; } o;
    asm("v_cvt_pk_bf16_f32 %0, %1, %2" : "=v"(o.u[0]) : "v"(x.x), "v"(x.y));
    asm("v_cvt_pk_bf16_f32 %0, %1, %2" : "=v"(o.u[1]) : "v"(x.z), "v"(x.w));
    asm("v_cvt_pk_bf16_f32 %0, %1, %2" : "=v"(o.u[2]) : "v"(y.x), "v"(y.y));
    asm("v_cvt_pk_bf16_f32 %0, %1, %2" : "=v"(o.u[3]) : "v"(y.z), "v"(y.w));
    return o.s;
}
template<int N> __device__ __forceinline__ void vm_wait() {
    if constexpr (N == 0) asm volatile("s_waitcnt vmcnt(0)" ::: "memory");
    else if constexpr (N == 3) asm volatile("s_waitcnt vmcnt(3)" ::: "memory");
    else if constexpr (N == 6) asm volatile("s_waitcnt vmcnt(6)" ::: "memory");
    else asm volatile("s_waitcnt vmcnt(9)" ::: "memory");
}
// LDS-visibility barrier that does NOT drain vmcnt (keeps the staging pipeline alive)
__device__ __forceinline__ void lds_sync() {
    asm volatile("s_waitcnt lgkmcnt(0)" ::: "memory");
    __builtin_amdgcn_s_barrier();
    __builtin_amdgcn_sched_barrier(0);
}

// ---- weight pre-conversion + fragment packing ----
__global__ __launch_bounds__(256)
void cvt_weights(const float* __restrict__ vfc, const float* __restrict__ afc,
                 const float* __restrict__ am,  const float* __restrict__ Vw,
                 const float* __restrict__ Uw,  ushort* __restrict__ dst)
{
    int f = blockIdx.x * 256 + threadIdx.x;
    if (f >= WTOT / 8) return;
    int e0 = f * 8;
    const float* src; int base, K;
    if      (e0 < WOFF_AFC) { src = vfc; base = WOFF_VFC; K = 512; }
    else if (e0 < WOFF_AM)  { src = afc; base = WOFF_AFC; K = 128; }
    else if (e0 < WOFF_V)   { src = am;  base = WOFF_AM;  K = 128; }
    else if (e0 < WOFF_U)   { src = Vw;  base = WOFF_V;   K = 128; }
    else                    { src = Uw;  base = WOFF_U;   K = 128; }
    int lf = f - base / 8;
    int l = lf & 63, rem = lf >> 6;
    int NK = K / 32;
    int kc = rem % NK, n = rem / NK;
    int tc = l & 15, g4 = l >> 4;
    const float* sp = src + (size_t)(n * 16 + tc) * K + kc * 32 + g4 * 8;
    float4 x = ((const float4*)sp)[0], y = ((const float4*)sp)[1];
    short8 o = pack8(x, y);
    *(short8*)(dst + e0) = o;
}

// Stage one bundle: A chunk [128][32] f32 (2 gload_lds/wave, inverse-swizzled source)
// + one packed-B fragment per wave (8 waves cover n=0..7). 3 vmcnt entries per wave.
__device__ __forceinline__ void stage_bundle(const float* __restrict__ srcA, int ldK, int kcol,
                                             const ushort* __restrict__ srcB,  // + (wid*NK+kc)*512
                                             float* Ab, ushort* Bb, int wid, int lane)
{
    #pragma unroll
    for (int i = 0; i < 2; ++i) {
        int D   = i * 512 + wid * 64 + lane;
        int row = D >> 3, jj = D & 7;
        int j   = jj ^ (row & 7);
        const float* gp = srcA + (size_t)row * ldK + kcol + j * 4;
        float* lp = Ab + (i * 512 + wid * 64) * 4;
        __builtin_amdgcn_global_load_lds((const __attribute__((address_space(1))) void*)gp,
                                         (__attribute__((address_space(3))) void*)lp, 16, 0, 0);
    }
    const ushort* gpb = srcB + lane * 8;
    ushort* lpb = Bb + wid * 512;
    __builtin_amdgcn_global_load_lds((const __attribute__((address_space(1))) void*)gpb,
                                     (__attribute__((address_space(3))) void*)lpb, 16, 0, 0);
}

// Compute one staged chunk: A from Abuf (f32, fswz), B from Bbuf (bf16 frags), 8 MFMA.
__device__ __forceinline__ void chunk_mfma(const float* __restrict__ Ab,
                                           const ushort* __restrict__ Bb,
                                           int wr, int wc, int t16, int g4, int lane,
                                           f32x4 (&acc)[2][4])
{
    int row0 = 32 * wr + t16;
    float4 x0 = *(const float4*)&Ab[fswz(row0,      2 * g4)];
    float4 y0 = *(const float4*)&Ab[fswz(row0,      2 * g4 + 1)];
    float4 x1 = *(const float4*)&Ab[fswz(row0 + 16, 2 * g4)];
    float4 y1 = *(const float4*)&Ab[fswz(row0 + 16, 2 * g4 + 1)];
    short8 a0 = pack8(x0, y0), a1 = pack8(x1, y1);
    #pragma unroll
    for (int n = 0; n < 4; ++n) {
        short8 b = *(const short8*)&Bb[(4 * wc + n) * 512 + lane * 8];
        acc[0][n] = __builtin_amdgcn_mfma_f32_16x16x32_bf16(a0, b, acc[0][n], 0, 0, 0);
        acc[1][n] = __builtin_amdgcn_mfma_f32_16x16x32_bf16(a1, b, acc[1][n], 0, 0, 0);
    }
}

// Grid: 32 b x 16 tiles = 512 blocks, 512 threads (8 waves).
// LDS 152KB -> 1 block/CU. Unified 20-chunk staged stream (16 vfeat + 4 afeat),
// depth 4, 5 buffers, counted vmcnt(9) steady-state (never drained mid-stream).
__global__ __launch_bounds__(THREADS, 1)
void fused_mil(const float* __restrict__ vfeat, const float* __restrict__ afeat,
               const ushort* __restrict__ wsW,
               const float* __restrict__ afc_b, const float* __restrict__ am_b,
               const float* __restrict__ vfc_b,
               const float* __restrict__ V_b,   const float* __restrict__ U_b,
               const float* __restrict__ W_w,   const float* __restrict__ W_b,
               float* __restrict__ s_out, float* __restrict__ zpart)
{
    __shared__ __align__(16) float  Abuf[5][128 * 32];   // 80 KB
    __shared__ __align__(16) ushort Bbuf[5][8 * 512];    // 40 KB
    __shared__ __align__(16) ushort Xbuf[128 * 128];     // 32 KB: ax -> gate -> ffeat

    // scratch aliased into Abuf[0] (only used after all staging retired)
    float* sPb = (float*)&Abuf[0][0];   // [2][128]
    float* sSb = sPb + 256;             // [128]
    float* zqb = sSb + 128;             // [4][128]

    const int tid  = threadIdx.x;
    const int bx   = blockIdx.x;
    const int b    = bx >> 4;
    const int tok0 = (bx & 15) * TM;
    const int wid  = tid >> 6;
    const int lane = tid & 63;
    const int t16  = lane & 15;
    const int g4   = lane >> 4;
    const int wr   = wid >> 1;
    const int wc   = wid & 1;

    const float* afeat_t = afeat + ((size_t)b * N_ + tok0) * AD_;
    const float* vfeat_t = vfeat + ((size_t)b * N_ + tok0) * VD_;

    f32x4 accC[2][4], accA[2][4];
    #pragma unroll
    for (int m = 0; m < 2; ++m)
        #pragma unroll
        for (int n = 0; n < 4; ++n) { accC[m][n] = (f32x4)0.0f; accA[m][n] = (f32x4)0.0f; }

    // ---- unified staged stream: chunks 0..15 = vfeat/vfc, 16..19 = afeat/afc ----
    #define ISSUE(t)                                                                        \
        do {                                                                                \
            if ((t) < 16) stage_bundle(vfeat_t, VD_, (t) * 32,                              \
                                       wsW + WOFF_VFC + ((size_t)(wid * 16 + (t))) * 512,   \
                                       Abuf[(t) % 5], Bbuf[(t) % 5], wid, lane);            \
            else          stage_bundle(afeat_t, AD_, ((t) - 16) * 32,                       \
                                       wsW + WOFF_AFC + ((size_t)(wid * 4 + (t) - 16)) * 512,\
                                       Abuf[(t) % 5], Bbuf[(t) % 5], wid, lane);            \
        } while (0)

    #pragma unroll
    for (int t = 0; t < 4; ++t) ISSUE(t);

    #pragma unroll
    for (int k = 0; k < 20; ++k) {
        if (k < 17)      vm_wait<9>();
        else if (k == 17) vm_wait<6>();
        else if (k == 18) vm_wait<3>();
        else              vm_wait<0>();
        __builtin_amdgcn_s_barrier();
        __builtin_amdgcn_sched_barrier(0);
        if (k + 4 < 20) ISSUE(k + 4);
        if (k < 16) chunk_mfma(Abuf[k % 5], Bbuf[k % 5], wr, wc, t16, g4, lane, accC);
        else        chunk_mfma(Abuf[k % 5], Bbuf[k % 5], wr, wc, t16, g4, lane, accA);
    }
    #undef ISSUE

    // ---- ax = relu(accA + afc_b) -> Xbuf ----
    #pragma unroll
    for (int n = 0; n < 4; ++n) {
        int c = 64 * wc + 16 * n + t16;
        float bias = afc_b[c];
        #pragma unroll
        for (int m = 0; m < 2; ++m)
            #pragma unroll
            for (int r = 0; r < 4; ++r) {
                int row = 32 * wr + 16 * m + 4 * g4 + r;
                Xbuf[swz(row, c, 128)] = f2bf(fmaxf(accA[m][n][r] + bias, 0.0f));
            }
    }
    lds_sync();                                        // ax visible to all waves

    // ---- gate = sigmoid(ax @ am_w^T + am_b) (plain L2 B-loads; FIFO empty now) ----
    f32x4 accB[2][4];
    #pragma unroll
    for (int m = 0; m < 2; ++m)
        #pragma unroll
        for (int n = 0; n < 4; ++n) accB[m][n] = (f32x4)0.0f;
    #pragma unroll
    for (int kc = 0; kc < 4; ++kc) {
        int kk = kc * 32 + g4 * 8;
        short8 a0 = *(const short8*)&Xbuf[swz(32 * wr + t16,      kk, 128)];
        short8 a1 = *(const short8*)&Xbuf[swz(32 * wr + 16 + t16, kk, 128)];
        #pragma unroll
        for (int n = 0; n < 4; ++n) {
            short8 bmat = *(const short8*)(wsW + WOFF_AM + ((size_t)((4 * wc + n) * 4 + kc)) * 512 + lane * 8);
            accB[0][n] = __builtin_amdgcn_mfma_f32_16x16x32_bf16(a0, bmat, accB[0][n], 0, 0, 0);
            accB[1][n] = __builtin_amdgcn_mfma_f32_16x16x32_bf16(a1, bmat, accB[1][n], 0, 0, 0);
        }
    }
    lds_sync();                                        // all ax reads done

    // stash gate bf16 into own Xbuf cells
    #pragma unroll
    for (int n = 0; n < 4; ++n) {
        int c = 64 * wc + 16 * n + t16;
        float bias = am_b[c];
        #pragma unroll
        for (int m = 0; m < 2; ++m)
            #pragma unroll
            for (int r = 0; r < 4; ++r) {
                int row = 32 * wr + 16 * m + 4 * g4 + r;
                Xbuf[swz(row, c, 128)] = f2bf(sigmoidf_(accB[m][n][r] + bias));
            }
    }
    // no barrier: gate cells are thread-private

    // ---- ffeat = relu(vo1 + vfc_b) * (1 + gate) -> Xbuf ----
    #pragma unroll
    for (int n = 0; n < 4; ++n) {
        int c = 64 * wc + 16 * n + t16;
        float vb = vfc_b[c];
        #pragma unroll
        for (int m = 0; m < 2; ++m)
            #pragma unroll
            for (int r = 0; r < 4; ++r) {
                int row = 32 * wr + 16 * m + 4 * g4 + r;
                float g   = bf2f(Xbuf[swz(row, c, 128)]);
                float vo1 = fmaxf(accC[m][n][r] + vb, 0.0f);
                Xbuf[swz(row, c, 128)] = f2bf(vo1 * (1.0f + g));
            }
    }
    lds_sync();                                        // ffeat visible

    // ---- v/u heads: n=0,1 -> V tiles 2wc+n; n=2,3 -> U tiles 2wc+(n-2) ----
    #pragma unroll
    for (int m = 0; m < 2; ++m)
        #pragma unroll
        for (int n = 0; n < 4; ++n) accB[m][n] = (f32x4)0.0f;
    {
        const ushort* Vp = wsW + WOFF_V;
        const ushort* Up = wsW + WOFF_U;
        #pragma unroll
        for (int kc = 0; kc < 4; ++kc) {
            int kk = kc * 32 + g4 * 8;
            short8 a0 = *(const short8*)&Xbuf[swz(32 * wr + t16,      kk, 128)];
            short8 a1 = *(const short8*)&Xbuf[swz(32 * wr + 16 + t16, kk, 128)];
            #pragma unroll
            for (int n = 0; n < 2; ++n) {
                short8 bv = *(const short8*)(Vp + ((size_t)(2 * wc + n) * 4 + kc) * 512 + lane * 8);
                short8 bu = *(const short8*)(Up + ((size_t)(2 * wc + n) * 4 + kc) * 512 + lane * 8);
                accB[0][n]     = __builtin_amdgcn_mfma_f32_16x16x32_bf16(a0, bv, accB[0][n],     0, 0, 0);
                accB[1][n]     = __builtin_amdgcn_mfma_f32_16x16x32_bf16(a1, bv, accB[1][n],     0, 0, 0);
                accB[0][n + 2] = __builtin_amdgcn_mfma_f32_16x16x32_bf16(a0, bu, accB[0][n + 2], 0, 0, 0);
                accB[1][n + 2] = __builtin_amdgcn_mfma_f32_16x16x32_bf16(a1, bu, accB[1][n + 2], 0, 0, 0);
            }
        }
    }

    // ---- score s = sum_h relu(v)*sigmoid(u)*W_w + W_b ----
    #pragma unroll
    for (int m = 0; m < 2; ++m)
        #pragma unroll
        for (int r = 0; r < 4; ++r) {
            float p = 0.0f;
            #pragma unroll
            for (int n = 0; n < 2; ++n) {
                int h = 32 * wc + 16 * n + t16;
                float vv = fmaxf(accB[m][n][r] + V_b[h], 0.0f);
                float uu = sigmoidf_(accB[m][n + 2][r] + U_b[h]);
                p = fmaf(vv * uu, W_w[h], p);
            }
            p += __shfl_xor(p, 1);
            p += __shfl_xor(p, 2);
            p += __shfl_xor(p, 4);
            p += __shfl_xor(p, 8);
            if (t16 == 0) sPb[wc * 128 + 32 * wr + 16 * m + 4 * g4 + r] = p;
        }
    __syncthreads();
    if (tid < 128) {
        float s = sPb[tid] + sPb[128 + tid] + W_b[0];
        sSb[tid] = s;
        s_out[(size_t)b * N_ + tok0 + tid] = s;
    }
    __syncthreads();

    // ---- zpart[k] = sum_t s[t] * ffeat[t][k] ----
    {
        int k = tid & 127, q = tid >> 7;
        float z = 0.0f;
        #pragma unroll
        for (int t = 0; t < 32; ++t) {
            int row = q * 32 + t;
            z = fmaf(sSb[row], bf2f(Xbuf[swz(row, k, 128)]), z);
        }
        zqb[q * 128 + k] = z;
    }
    __syncthreads();
    if (tid < 128)
        zpart[(size_t)bx * 128 + tid] = zqb[tid] + zqb[128 + tid] + zqb[256 + tid] + zqb[384 + tid];
}

// Grid: 32 blocks, 128 threads.
__global__ __launch_bounds__(128)
void reduce_logits(const float* __restrict__ zpart,
                   const float* __restrict__ cls_w, const float* __restrict__ cls_b,
                   float* __restrict__ out)
{
    __shared__ float sZ[128];
    int b = blockIdx.x, k = threadIdx.x;
    float z = 0.0f;
    #pragma unroll
    for (int t = 0; t < 16; ++t) z += zpart[(size_t)(b * 16 + t) * 128 + k];
    sZ[k] = z;
    __syncthreads();
    if (k < 2) {
        float acc = cls_b[k];
        for (int i = 0; i < 128; ++i) acc = fmaf(sZ[i], cls_w[k * 128 + i], acc);
        out[(size_t)B_ * N_ + b * 2 + k] = acc;
    }
}

extern "C" void kernel_launch(void* const* d_in, const int* in_sizes, int n_in,
                              void* d_out, int out_size, void* d_ws, size_t ws_size,
                              hipStream_t stream) {
    const float* vfeat = (const float*)d_in[0];
    const float* afeat = (const float*)d_in[1];
    const float* vfc_w = (const float*)d_in[2];
    const float* vfc_b = (const float*)d_in[3];
    const float* afc_w = (const float*)d_in[4];
    const float* afc_b = (const float*)d_in[5];
    const float* am_w  = (const float*)d_in[6];
    const float* am_b  = (const float*)d_in[7];
    const float* U_w   = (const float*)d_in[8];
    const float* U_b   = (const float*)d_in[9];
    const float* V_w   = (const float*)d_in[10];
    const float* V_b   = (const float*)d_in[11];
    const float* W_w   = (const float*)d_in[12];
    const float* W_b   = (const float*)d_in[13];
    const float* cls_w = (const float*)d_in[14];
    const float* cls_b = (const float*)d_in[15];

    float* out   = (float*)d_out;
    ushort* wsW  = (ushort*)d_ws;                            // 229376 B packed bf16 weights
    float* zpart = (float*)((char*)d_ws + (size_t)WTOT * 2); // 512*128*4 = 256 KB

    cvt_weights<<<dim3((WTOT / 8 + 255) / 256), dim3(256), 0, stream>>>(vfc_w, afc_w, am_w, V_w, U_w, wsW);
    fused_mil<<<dim3(B_ * 16), dim3(THREADS), 0, stream>>>(
        vfeat, afeat, wsW, afc_b, am_b, vfc_b, V_b, U_b, W_w, W_b, out, zpart);
    reduce_logits<<<dim3(B_), dim3(128), 0, stream>>>(zpart, cls_w, cls_b, out);
}

// Round 10
// 59.536 us; speedup vs baseline: 1.8948x; 1.0027x over previous
//
#include <hip/hip_runtime.h>
#include <hip/hip_bf16.h>

#define B_   32
#define N_   2048
#define VD_  512
#define AD_  128
#define SD_  128
#define TM   128
#define THREADS 512

typedef __attribute__((ext_vector_type(8))) short short8;
typedef __attribute__((ext_vector_type(4))) float f32x4;

// ws layout (ushort element offsets) for fragment-packed bf16 weights.
// Packing: for W[C][K], frag (n,kc,l,e): dst[((n*(K/32)+kc)*64+l)*8+e] = W[n*16+(l&15)][kc*32+(l>>4)*8+e]
#define WOFF_VFC 0        // C=128,K=512: 65536
#define WOFF_AFC 65536    // C=128,K=128: 16384
#define WOFF_AM  81920    // C=128,K=128: 16384
#define WOFF_V   98304    // C=64, K=128: 8192
#define WOFF_U   106496   // C=64, K=128: 8192
#define WTOT     114688   // ushorts = 229376 bytes; zpart follows

__device__ __forceinline__ float sigmoidf_(float x) { return 1.0f / (1.0f + __expf(-x)); }

__device__ __forceinline__ ushort f2bf(float x) {   // RNE
    union { float f; unsigned int i; } v; v.f = x;
    unsigned int r = v.i + 0x7FFFu + ((v.i >> 16) & 1u);
    return (ushort)(r >> 16);
}
__device__ __forceinline__ float bf2f(ushort u) {
    union { unsigned int i; float f; } v; v.i = ((unsigned int)u) << 16; return v.f;
}
// Xbuf swizzle: ushort [128][128], XOR on 16B chunks
__device__ __forceinline__ int swz(int row, int k, int ldk) {
    return row * ldk + (k ^ ((row & 7) << 3));
}
// Abuf swizzle: f32 [128][32], (row, 16B-chunk c) -> f32 index
__device__ __forceinline__ int fswz(int row, int c) {
    return row * 32 + ((c ^ (row & 7)) << 2);
}
// 8x f32 -> 8x bf16 packed convert (RNE)
__device__ __forceinline__ short8 pack8(float4 x, float4 y) {
    union { unsigned int u[4]; short8 s; } o;
    asm("v_cvt_pk_bf16_f32 %0, %1, %2" : "=v"(o.u[0]) : "v"(x.x), "v"(x.y));
    asm("v_cvt_pk_bf16_f32 %0, %1, %2" : "=v"(o.u[1]) : "v"(x.z), "v"(x.w));
    asm("v_cvt_pk_bf16_f32 %0, %1, %2" : "=v"(o.u[2]) : "v"(y.x), "v"(y.y));
    asm("v_cvt_pk_bf16_f32 %0, %1, %2" : "=v"(o.u[3]) : "v"(y.z), "v"(y.w));
    return o.s;
}
template<int N> __device__ __forceinline__ void vm_wait() {
    if constexpr (N == 0) asm volatile("s_waitcnt vmcnt(0)" ::: "memory");
    else if constexpr (N == 3) asm volatile("s_waitcnt vmcnt(3)" ::: "memory");
    else if constexpr (N == 6) asm volatile("s_waitcnt vmcnt(6)" ::: "memory");
    else asm volatile("s_waitcnt vmcnt(9)" ::: "memory");
}
// LDS-visibility barrier that does NOT drain vmcnt (keeps the staging pipeline alive)
__device__ __forceinline__ void lds_sync() {
    asm volatile("s_waitcnt lgkmcnt(0)" ::: "memory");
    __builtin_amdgcn_s_barrier();
    __builtin_amdgcn_sched_barrier(0);
}

// ---- weight pre-conversion + fragment packing ----
__global__ __launch_bounds__(256)
void cvt_weights(const float* __restrict__ vfc, const float* __restrict__ afc,
                 const float* __restrict__ am,  const float* __restrict__ Vw,
                 const float* __restrict__ Uw,  ushort* __restrict__ dst)
{
    int f = blockIdx.x * 256 + threadIdx.x;
    if (f >= WTOT / 8) return;
    int e0 = f * 8;
    const float* src; int base, K;
    if      (e0 < WOFF_AFC) { src = vfc; base = WOFF_VFC; K = 512; }
    else if (e0 < WOFF_AM)  { src = afc; base = WOFF_AFC; K = 128; }
    else if (e0 < WOFF_V)   { src = am;  base = WOFF_AM;  K = 128; }
    else if (e0 < WOFF_U)   { src = Vw;  base = WOFF_V;   K = 128; }
    else                    { src = Uw;  base = WOFF_U;   K = 128; }
    int lf = f - base / 8;
    int l = lf & 63, rem = lf >> 6;
    int NK = K / 32;
    int kc = rem % NK, n = rem / NK;
    int tc = l & 15, g4 = l >> 4;
    const float* sp = src + (size_t)(n * 16 + tc) * K + kc * 32 + g4 * 8;
    float4 x = ((const float4*)sp)[0], y = ((const float4*)sp)[1];
    short8 o = pack8(x, y);
    *(short8*)(dst + e0) = o;
}

// Stage one bundle: A chunk [128][32] f32 (2 gload_lds/wave, inverse-swizzled source)
// + one packed-B fragment per wave (8 waves cover n=0..7). 3 vmcnt entries per wave.
__device__ __forceinline__ void stage_bundle(const float* __restrict__ srcA, int ldK, int kcol,
                                             const ushort* __restrict__ srcB,  // + (wid*NK+kc)*512
                                             float* Ab, ushort* Bb, int wid, int lane)
{
    #pragma unroll
    for (int i = 0; i < 2; ++i) {
        int D   = i * 512 + wid * 64 + lane;
        int row = D >> 3, jj = D & 7;
        int j   = jj ^ (row & 7);
        const float* gp = srcA + (size_t)row * ldK + kcol + j * 4;
        float* lp = Ab + (i * 512 + wid * 64) * 4;
        __builtin_amdgcn_global_load_lds((const __attribute__((address_space(1))) void*)gp,
                                         (__attribute__((address_space(3))) void*)lp, 16, 0, 0);
    }
    const ushort* gpb = srcB + lane * 8;
    ushort* lpb = Bb + wid * 512;
    __builtin_amdgcn_global_load_lds((const __attribute__((address_space(1))) void*)gpb,
                                     (__attribute__((address_space(3))) void*)lpb, 16, 0, 0);
}

// Compute one staged chunk: A from Abuf (f32, fswz), B from Bbuf (bf16 frags), 8 MFMA.
__device__ __forceinline__ void chunk_mfma(const float* __restrict__ Ab,
                                           const ushort* __restrict__ Bb,
                                           int wr, int wc, int t16, int g4, int lane,
                                           f32x4 (&acc)[2][4])
{
    int row0 = 32 * wr + t16;
    float4 x0 = *(const float4*)&Ab[fswz(row0,      2 * g4)];
    float4 y0 = *(const float4*)&Ab[fswz(row0,      2 * g4 + 1)];
    float4 x1 = *(const float4*)&Ab[fswz(row0 + 16, 2 * g4)];
    float4 y1 = *(const float4*)&Ab[fswz(row0 + 16, 2 * g4 + 1)];
    short8 a0 = pack8(x0, y0), a1 = pack8(x1, y1);
    #pragma unroll
    for (int n = 0; n < 4; ++n) {
        short8 b = *(const short8*)&Bb[(4 * wc + n) * 512 + lane * 8];
        acc[0][n] = __builtin_amdgcn_mfma_f32_16x16x32_bf16(a0, b, acc[0][n], 0, 0, 0);
        acc[1][n] = __builtin_amdgcn_mfma_f32_16x16x32_bf16(a1, b, acc[1][n], 0, 0, 0);
    }
}

// Grid: 32 b x 16 tiles = 512 blocks, 512 threads (8 waves).
// LDS 152KB -> 1 block/CU. Unified 20-chunk staged stream (16 vfeat + 4 afeat),
// depth 4, 5 buffers, counted vmcnt(9) steady-state.
// NEW (R10): per-block K-chunk rotation so blocks don't stride HBM columns in
// lockstep (channel-collision fix): phys = (t + bx) & 15 (afeat: &3).
__global__ __launch_bounds__(THREADS, 1)
void fused_mil(const float* __restrict__ vfeat, const float* __restrict__ afeat,
               const ushort* __restrict__ wsW,
               const float* __restrict__ afc_b, const float* __restrict__ am_b,
               const float* __restrict__ vfc_b,
               const float* __restrict__ V_b,   const float* __restrict__ U_b,
               const float* __restrict__ W_w,   const float* __restrict__ W_b,
               float* __restrict__ s_out, float* __restrict__ zpart)
{
    __shared__ __align__(16) float  Abuf[5][128 * 32];   // 80 KB
    __shared__ __align__(16) ushort Bbuf[5][8 * 512];    // 40 KB
    __shared__ __align__(16) ushort Xbuf[128 * 128];     // 32 KB: ax -> gate -> ffeat

    // scratch aliased into Abuf[0] (only used after all staging retired)
    float* sPb = (float*)&Abuf[0][0];   // [2][128]
    float* sSb = sPb + 256;             // [128]
    float* zqb = sSb + 128;             // [4][128]

    const int tid  = threadIdx.x;
    const int bx   = blockIdx.x;
    const int b    = bx >> 4;
    const int tok0 = (bx & 15) * TM;
    const int wid  = tid >> 6;
    const int lane = tid & 63;
    const int t16  = lane & 15;
    const int g4   = lane >> 4;
    const int wr   = wid >> 1;
    const int wc   = wid & 1;
    const int rotv = bx & 15;           // vfeat K-chunk rotation
    const int rota = bx & 3;            // afeat K-chunk rotation

    const float* afeat_t = afeat + ((size_t)b * N_ + tok0) * AD_;
    const float* vfeat_t = vfeat + ((size_t)b * N_ + tok0) * VD_;

    f32x4 accC[2][4], accA[2][4];
    #pragma unroll
    for (int m = 0; m < 2; ++m)
        #pragma unroll
        for (int n = 0; n < 4; ++n) { accC[m][n] = (f32x4)0.0f; accA[m][n] = (f32x4)0.0f; }

    // ---- unified staged stream: chunks 0..15 = vfeat/vfc, 16..19 = afeat/afc ----
    // Buffers indexed by logical t (ring); HBM addresses by rotated phys index.
    #define ISSUE(t)                                                                        \
        do {                                                                                \
            if ((t) < 16) {                                                                 \
                int phys = ((t) + rotv) & 15;                                               \
                stage_bundle(vfeat_t, VD_, phys * 32,                                       \
                             wsW + WOFF_VFC + ((size_t)(wid * 16 + phys)) * 512,            \
                             Abuf[(t) % 5], Bbuf[(t) % 5], wid, lane);                      \
            } else {                                                                        \
                int phys = ((t) - 16 + rota) & 3;                                           \
                stage_bundle(afeat_t, AD_, phys * 32,                                       \
                             wsW + WOFF_AFC + ((size_t)(wid * 4 + phys)) * 512,             \
                             Abuf[(t) % 5], Bbuf[(t) % 5], wid, lane);                      \
            }                                                                               \
        } while (0)

    #pragma unroll
    for (int t = 0; t < 4; ++t) ISSUE(t);

    #pragma unroll
    for (int k = 0; k < 20; ++k) {
        if (k < 17)      vm_wait<9>();
        else if (k == 17) vm_wait<6>();
        else if (k == 18) vm_wait<3>();
        else              vm_wait<0>();
        __builtin_amdgcn_s_barrier();
        __builtin_amdgcn_sched_barrier(0);
        if (k + 4 < 20) ISSUE(k + 4);
        if (k < 16) chunk_mfma(Abuf[k % 5], Bbuf[k % 5], wr, wc, t16, g4, lane, accC);
        else        chunk_mfma(Abuf[k % 5], Bbuf[k % 5], wr, wc, t16, g4, lane, accA);
    }
    #undef ISSUE

    // ---- ax = relu(accA + afc_b) -> Xbuf ----
    #pragma unroll
    for (int n = 0; n < 4; ++n) {
        int c = 64 * wc + 16 * n + t16;
        float bias = afc_b[c];
        #pragma unroll
        for (int m = 0; m < 2; ++m)
            #pragma unroll
            for (int r = 0; r < 4; ++r) {
                int row = 32 * wr + 16 * m + 4 * g4 + r;
                Xbuf[swz(row, c, 128)] = f2bf(fmaxf(accA[m][n][r] + bias, 0.0f));
            }
    }
    lds_sync();                                        // ax visible to all waves

    // ---- gate = sigmoid(ax @ am_w^T + am_b) (plain L2 B-loads; FIFO empty now) ----
    f32x4 accB[2][4];
    #pragma unroll
    for (int m = 0; m < 2; ++m)
        #pragma unroll
        for (int n = 0; n < 4; ++n) accB[m][n] = (f32x4)0.0f;
    #pragma unroll
    for (int kc = 0; kc < 4; ++kc) {
        int kk = kc * 32 + g4 * 8;
        short8 a0 = *(const short8*)&Xbuf[swz(32 * wr + t16,      kk, 128)];
        short8 a1 = *(const short8*)&Xbuf[swz(32 * wr + 16 + t16, kk, 128)];
        #pragma unroll
        for (int n = 0; n < 4; ++n) {
            short8 bmat = *(const short8*)(wsW + WOFF_AM + ((size_t)((4 * wc + n) * 4 + kc)) * 512 + lane * 8);
            accB[0][n] = __builtin_amdgcn_mfma_f32_16x16x32_bf16(a0, bmat, accB[0][n], 0, 0, 0);
            accB[1][n] = __builtin_amdgcn_mfma_f32_16x16x32_bf16(a1, bmat, accB[1][n], 0, 0, 0);
        }
    }
    lds_sync();                                        // all ax reads done

    // stash gate bf16 into own Xbuf cells
    #pragma unroll
    for (int n = 0; n < 4; ++n) {
        int c = 64 * wc + 16 * n + t16;
        float bias = am_b[c];
        #pragma unroll
        for (int m = 0; m < 2; ++m)
            #pragma unroll
            for (int r = 0; r < 4; ++r) {
                int row = 32 * wr + 16 * m + 4 * g4 + r;
                Xbuf[swz(row, c, 128)] = f2bf(sigmoidf_(accB[m][n][r] + bias));
            }
    }
    // no barrier: gate cells are thread-private

    // ---- ffeat = relu(vo1 + vfc_b) * (1 + gate) -> Xbuf ----
    #pragma unroll
    for (int n = 0; n < 4; ++n) {
        int c = 64 * wc + 16 * n + t16;
        float vb = vfc_b[c];
        #pragma unroll
        for (int m = 0; m < 2; ++m)
            #pragma unroll
            for (int r = 0; r < 4; ++r) {
                int row = 32 * wr + 16 * m + 4 * g4 + r;
                float g   = bf2f(Xbuf[swz(row, c, 128)]);
                float vo1 = fmaxf(accC[m][n][r] + vb, 0.0f);
                Xbuf[swz(row, c, 128)] = f2bf(vo1 * (1.0f + g));
            }
    }
    lds_sync();                                        // ffeat visible

    // ---- v/u heads: n=0,1 -> V tiles 2wc+n; n=2,3 -> U tiles 2wc+(n-2) ----
    #pragma unroll
    for (int m = 0; m < 2; ++m)
        #pragma unroll
        for (int n = 0; n < 4; ++n) accB[m][n] = (f32x4)0.0f;
    {
        const ushort* Vp = wsW + WOFF_V;
        const ushort* Up = wsW + WOFF_U;
        #pragma unroll
        for (int kc = 0; kc < 4; ++kc) {
            int kk = kc * 32 + g4 * 8;
            short8 a0 = *(const short8*)&Xbuf[swz(32 * wr + t16,      kk, 128)];
            short8 a1 = *(const short8*)&Xbuf[swz(32 * wr + 16 + t16, kk, 128)];
            #pragma unroll
            for (int n = 0; n < 2; ++n) {
                short8 bv = *(const short8*)(Vp + ((size_t)(2 * wc + n) * 4 + kc) * 512 + lane * 8);
                short8 bu = *(const short8*)(Up + ((size_t)(2 * wc + n) * 4 + kc) * 512 + lane * 8);
                accB[0][n]     = __builtin_amdgcn_mfma_f32_16x16x32_bf16(a0, bv, accB[0][n],     0, 0, 0);
                accB[1][n]     = __builtin_amdgcn_mfma_f32_16x16x32_bf16(a1, bv, accB[1][n],     0, 0, 0);
                accB[0][n + 2] = __builtin_amdgcn_mfma_f32_16x16x32_bf16(a0, bu, accB[0][n + 2], 0, 0, 0);
                accB[1][n + 2] = __builtin_amdgcn_mfma_f32_16x16x32_bf16(a1, bu, accB[1][n + 2], 0, 0, 0);
            }
        }
    }

    // ---- score s = sum_h relu(v)*sigmoid(u)*W_w + W_b ----
    #pragma unroll
    for (int m = 0; m < 2; ++m)
        #pragma unroll
        for (int r = 0; r < 4; ++r) {
            float p = 0.0f;
            #pragma unroll
            for (int n = 0; n < 2; ++n) {
                int h = 32 * wc + 16 * n + t16;
                float vv = fmaxf(accB[m][n][r] + V_b[h], 0.0f);
                float uu = sigmoidf_(accB[m][n + 2][r] + U_b[h]);
                p = fmaf(vv * uu, W_w[h], p);
            }
            p += __shfl_xor(p, 1);
            p += __shfl_xor(p, 2);
            p += __shfl_xor(p, 4);
            p += __shfl_xor(p, 8);
            if (t16 == 0) sPb[wc * 128 + 32 * wr + 16 * m + 4 * g4 + r] = p;
        }
    __syncthreads();
    if (tid < 128) {
        float s = sPb[tid] + sPb[128 + tid] + W_b[0];
        sSb[tid] = s;
        s_out[(size_t)b * N_ + tok0 + tid] = s;
    }
    __syncthreads();

    // ---- zpart[k] = sum_t s[t] * ffeat[t][k] ----
    {
        int k = tid & 127, q = tid >> 7;
        float z = 0.0f;
        #pragma unroll
        for (int t = 0; t < 32; ++t) {
            int row = q * 32 + t;
            z = fmaf(sSb[row], bf2f(Xbuf[swz(row, k, 128)]), z);
        }
        zqb[q * 128 + k] = z;
    }
    __syncthreads();
    if (tid < 128)
        zpart[(size_t)bx * 128 + tid] = zqb[tid] + zqb[128 + tid] + zqb[256 + tid] + zqb[384 + tid];
}

// Grid: 32 blocks, 128 threads.
__global__ __launch_bounds__(128)
void reduce_logits(const float* __restrict__ zpart,
                   const float* __restrict__ cls_w, const float* __restrict__ cls_b,
                   float* __restrict__ out)
{
    __shared__ float sZ[128];
    int b = blockIdx.x, k = threadIdx.x;
    float z = 0.0f;
    #pragma unroll
    for (int t = 0; t < 16; ++t) z += zpart[(size_t)(b * 16 + t) * 128 + k];
    sZ[k] = z;
    __syncthreads();
    if (k < 2) {
        float acc = cls_b[k];
        for (int i = 0; i < 128; ++i) acc = fmaf(sZ[i], cls_w[k * 128 + i], acc);
        out[(size_t)B_ * N_ + b * 2 + k] = acc;
    }
}

extern "C" void kernel_launch(void* const* d_in, const int* in_sizes, int n_in,
                              void* d_out, int out_size, void* d_ws, size_t ws_size,
                              hipStream_t stream) {
    const float* vfeat = (const float*)d_in[0];
    const float* afeat = (const float*)d_in[1];
    const float* vfc_w = (const float*)d_in[2];
    const float* vfc_b = (const float*)d_in[3];
    const float* afc_w = (const float*)d_in[4];
    const float* afc_b = (const float*)d_in[5];
    const float* am_w  = (const float*)d_in[6];
    const float* am_b  = (const float*)d_in[7];
    const float* U_w   = (const float*)d_in[8];
    const float* U_b   = (const float*)d_in[9];
    const float* V_w   = (const float*)d_in[10];
    const float* V_b   = (const float*)d_in[11];
    const float* W_w   = (const float*)d_in[12];
    const float* W_b   = (const float*)d_in[13];
    const float* cls_w = (const float*)d_in[14];
    const float* cls_b = (const float*)d_in[15];

    float* out   = (float*)d_out;
    ushort* wsW  = (ushort*)d_ws;                            // 229376 B packed bf16 weights
    float* zpart = (float*)((char*)d_ws + (size_t)WTOT * 2); // 512*128*4 = 256 KB

    cvt_weights<<<dim3((WTOT / 8 + 255) / 256), dim3(256), 0, stream>>>(vfc_w, afc_w, am_w, V_w, U_w, wsW);
    fused_mil<<<dim3(B_ * 16), dim3(THREADS), 0, stream>>>(
        vfeat, afeat, wsW, afc_b, am_b, vfc_b, V_b, U_b, W_w, W_b, out, zpart);
    reduce_logits<<<dim3(B_), dim3(128), 0, stream>>>(zpart, cls_w, cls_b, out);
}

// Round 12
// 52.587 us; speedup vs baseline: 2.1452x; 1.1321x over previous
//
#include <hip/hip_runtime.h>
#include <hip/hip_bf16.h>

#define B_   32
#define N_   2048
#define VD_  512
#define AD_  128
#define SD_  128
#define TM   128
#define THREADS 512

typedef __attribute__((ext_vector_type(8))) short short8;
typedef __attribute__((ext_vector_type(4))) float f32x4;

// ws layout (ushort element offsets) for fragment-packed bf16 weights.
// Packing: for W[C][K], frag (n,kc,l,e): dst[((n*(K/32)+kc)*64+l)*8+e] = W[n*16+(l&15)][kc*32+(l>>4)*8+e]
#define WOFF_VFC 0        // C=128,K=512: 65536
#define WOFF_AFC 65536    // C=128,K=128: 16384
#define WOFF_AM  81920    // C=128,K=128: 16384
#define WOFF_V   98304    // C=64, K=128: 8192
#define WOFF_U   106496   // C=64, K=128: 8192
#define WTOT     114688   // ushorts = 229376 bytes; zpart follows

__device__ __forceinline__ float sigmoidf_(float x) { return 1.0f / (1.0f + __expf(-x)); }

__device__ __forceinline__ ushort f2bf(float x) {   // RNE
    union { float f; unsigned int i; } v; v.f = x;
    unsigned int r = v.i + 0x7FFFu + ((v.i >> 16) & 1u);
    return (ushort)(r >> 16);
}
__device__ __forceinline__ float bf2f(ushort u) {
    union { unsigned int i; float f; } v; v.i = ((unsigned int)u) << 16; return v.f;
}
// Xbuf swizzle: ushort [128][128], XOR on 16B chunks
__device__ __forceinline__ int swz(int row, int k, int ldk) {
    return row * ldk + (k ^ ((row & 7) << 3));
}
// Abuf swizzle: f32 [128][32], (row, 16B-chunk c) -> f32 index
__device__ __forceinline__ int fswz(int row, int c) {
    return row * 32 + ((c ^ (row & 7)) << 2);
}
// 8x f32 -> 8x bf16 packed convert (RNE)
__device__ __forceinline__ short8 pack8(float4 x, float4 y) {
    union { unsigned int u[4]; short8 s; } o;
    asm("v_cvt_pk_bf16_f32 %0, %1, %2" : "=v"(o.u[0]) : "v"(x.x), "v"(x.y));
    asm("v_cvt_pk_bf16_f32 %0, %1, %2" : "=v"(o.u[1]) : "v"(x.z), "v"(x.w));
    asm("v_cvt_pk_bf16_f32 %0, %1, %2" : "=v"(o.u[2]) : "v"(y.x), "v"(y.y));
    asm("v_cvt_pk_bf16_f32 %0, %1, %2" : "=v"(o.u[3]) : "v"(y.z), "v"(y.w));
    return o.s;
}
template<int N> __device__ __forceinline__ void vm_wait() {
    if constexpr (N == 0) asm volatile("s_waitcnt vmcnt(0)" ::: "memory");
    else asm volatile("s_waitcnt vmcnt(3)" ::: "memory");
}
// LDS-visibility barrier that does NOT drain vmcnt
__device__ __forceinline__ void lds_sync() {
    asm volatile("s_waitcnt lgkmcnt(0)" ::: "memory");
    __builtin_amdgcn_s_barrier();
    __builtin_amdgcn_sched_barrier(0);
}

// ---- weight pre-conversion + fragment packing ----
__global__ __launch_bounds__(256)
void cvt_weights(const float* __restrict__ vfc, const float* __restrict__ afc,
                 const float* __restrict__ am,  const float* __restrict__ Vw,
                 const float* __restrict__ Uw,  ushort* __restrict__ dst)
{
    int f = blockIdx.x * 256 + threadIdx.x;
    if (f >= WTOT / 8) return;
    int e0 = f * 8;
    const float* src; int base, K;
    if      (e0 < WOFF_AFC) { src = vfc; base = WOFF_VFC; K = 512; }
    else if (e0 < WOFF_AM)  { src = afc; base = WOFF_AFC; K = 128; }
    else if (e0 < WOFF_V)   { src = am;  base = WOFF_AM;  K = 128; }
    else if (e0 < WOFF_U)   { src = Vw;  base = WOFF_V;   K = 128; }
    else                    { src = Uw;  base = WOFF_U;   K = 128; }
    int lf = f - base / 8;
    int l = lf & 63, rem = lf >> 6;
    int NK = K / 32;
    int kc = rem % NK, n = rem / NK;
    int tc = l & 15, g4 = l >> 4;
    const float* sp = src + (size_t)(n * 16 + tc) * K + kc * 32 + g4 * 8;
    float4 x = ((const float4*)sp)[0], y = ((const float4*)sp)[1];
    short8 o = pack8(x, y);
    *(short8*)(dst + e0) = o;
}

// Stage one bundle: A chunk [128][32] f32 (2 gload_lds/wave, inverse-swizzled source)
// + one packed-B n-tile fragment per wave (8 waves cover n=0..7, 1KB each -> 8KB).
// 3 vmcnt entries per wave per bundle.
__device__ __forceinline__ void stage_bundle(const float* __restrict__ srcA, int ldK, int kcol,
                                             const ushort* __restrict__ srcB,
                                             float* Ab, ushort* Bb, int wid, int lane)
{
    #pragma unroll
    for (int i = 0; i < 2; ++i) {
        int D   = i * 512 + wid * 64 + lane;
        int row = D >> 3, jj = D & 7;
        int j   = jj ^ (row & 7);
        const float* gp = srcA + (size_t)row * ldK + kcol + j * 4;
        float* lp = Ab + (i * 512 + wid * 64) * 4;
        __builtin_amdgcn_global_load_lds((const __attribute__((address_space(1))) void*)gp,
                                         (__attribute__((address_space(3))) void*)lp, 16, 0, 0);
    }
    const ushort* gpb = srcB + lane * 8;
    ushort* lpb = Bb + wid * 512;
    __builtin_amdgcn_global_load_lds((const __attribute__((address_space(1))) void*)gpb,
                                     (__attribute__((address_space(3))) void*)lpb, 16, 0, 0);
}

// Compute one staged chunk: A from Abuf (f32, fswz), B from Bbuf (bf16 frags), 8 MFMA.
__device__ __forceinline__ void chunk_mfma(const float* __restrict__ Ab,
                                           const ushort* __restrict__ Bb,
                                           int wr, int wc, int t16, int g4, int lane,
                                           f32x4 (&acc)[2][4])
{
    int row0 = 32 * wr + t16;
    float4 x0 = *(const float4*)&Ab[fswz(row0,      2 * g4)];
    float4 y0 = *(const float4*)&Ab[fswz(row0,      2 * g4 + 1)];
    float4 x1 = *(const float4*)&Ab[fswz(row0 + 16, 2 * g4)];
    float4 y1 = *(const float4*)&Ab[fswz(row0 + 16, 2 * g4 + 1)];
    short8 a0 = pack8(x0, y0), a1 = pack8(x1, y1);
    #pragma unroll
    for (int n = 0; n < 4; ++n) {
        short8 b = *(const short8*)&Bb[(4 * wc + n) * 512 + lane * 8];
        acc[0][n] = __builtin_amdgcn_mfma_f32_16x16x32_bf16(a0, b, acc[0][n], 0, 0, 0);
        acc[1][n] = __builtin_amdgcn_mfma_f32_16x16x32_bf16(a1, b, acc[1][n], 0, 0, 0);
    }
}

// Grid: 32 b x 16 tiles = 512 blocks, 512 threads (8 waves).
// LDS = 3 x (16KB A + 8KB B) = 72KB -> 2 blocks/CU (R5's residency win).
// Unified 20-chunk stream (16 vfeat + 4 afeat), depth 2, counted vmcnt(3) (R9's win).
// Xbuf (32KB) + score scratch overlay the staging region; every overlay write happens
// after the post-loop lds_sync (all staging retired) -> unconditionally safe.
__global__ __launch_bounds__(THREADS, 4)
void fused_mil(const float* __restrict__ vfeat, const float* __restrict__ afeat,
               const ushort* __restrict__ wsW,
               const float* __restrict__ afc_b, const float* __restrict__ am_b,
               const float* __restrict__ vfc_b,
               const float* __restrict__ V_b,   const float* __restrict__ U_b,
               const float* __restrict__ W_w,   const float* __restrict__ W_b,
               float* __restrict__ s_out, float* __restrict__ zpart)
{
    __shared__ __align__(16) char smem[3 * 24576];   // 72 KB

    #define ABUF(i) ((float*)(smem + (size_t)(i) * 24576))
    #define BBUF(i) ((ushort*)(smem + (size_t)(i) * 24576 + 16384))
    ushort* Xbuf = (ushort*)smem;                 // 32KB overlay (valid after final lds_sync)
    float*  sPb  = (float*)(smem + 32768);        // [2][128]
    float*  sSb  = sPb + 256;                     // [128]
    float*  zqb  = sSb + 128;                     // [4][128]

    const int tid  = threadIdx.x;
    const int bx   = blockIdx.x;
    const int b    = bx >> 4;
    const int tok0 = (bx & 15) * TM;
    const int wid  = tid >> 6;
    const int lane = tid & 63;
    const int t16  = lane & 15;
    const int g4   = lane >> 4;
    const int wr   = wid >> 1;
    const int wc   = wid & 1;

    const float* afeat_t = afeat + ((size_t)b * N_ + tok0) * AD_;
    const float* vfeat_t = vfeat + ((size_t)b * N_ + tok0) * VD_;

    f32x4 accC[2][4], accA[2][4];
    #pragma unroll
    for (int m = 0; m < 2; ++m)
        #pragma unroll
        for (int n = 0; n < 4; ++n) { accC[m][n] = (f32x4)0.0f; accA[m][n] = (f32x4)0.0f; }

    // ---- unified staged stream: chunks 0..15 = vfeat/vfc, 16..19 = afeat/afc ----
    #define ISSUE(t)                                                                        \
        do {                                                                                \
            if ((t) < 16) stage_bundle(vfeat_t, VD_, (t) * 32,                              \
                                       wsW + WOFF_VFC + ((size_t)(wid * 16 + (t))) * 512,   \
                                       ABUF((t) % 3), BBUF((t) % 3), wid, lane);            \
            else          stage_bundle(afeat_t, AD_, ((t) - 16) * 32,                       \
                                       wsW + WOFF_AFC + ((size_t)(wid * 4 + (t) - 16)) * 512,\
                                       ABUF((t) % 3), BBUF((t) % 3), wid, lane);            \
        } while (0)

    ISSUE(0); ISSUE(1);

    #pragma unroll
    for (int k = 0; k < 20; ++k) {
        if (k < 19) vm_wait<3>();
        else        vm_wait<0>();
        __builtin_amdgcn_s_barrier();
        __builtin_amdgcn_sched_barrier(0);
        if (k + 2 < 20) ISSUE(k + 2);
        if (k < 16) chunk_mfma(ABUF(k % 3), BBUF(k % 3), wr, wc, t16, g4, lane, accC);
        else        chunk_mfma(ABUF(k % 3), BBUF(k % 3), wr, wc, t16, g4, lane, accA);
    }
    #undef ISSUE

    lds_sync();                                        // all staging retired (overlay safety)

    // ---- ax = relu(accA + afc_b) -> Xbuf ----
    #pragma unroll
    for (int n = 0; n < 4; ++n) {
        int c = 64 * wc + 16 * n + t16;
        float bias = afc_b[c];
        #pragma unroll
        for (int m = 0; m < 2; ++m)
            #pragma unroll
            for (int r = 0; r < 4; ++r) {
                int row = 32 * wr + 16 * m + 4 * g4 + r;
                Xbuf[swz(row, c, 128)] = f2bf(fmaxf(accA[m][n][r] + bias, 0.0f));
            }
    }
    lds_sync();                                        // ax visible to all waves

    // ---- gate = sigmoid(ax @ am_w^T + am_b) (plain L2 B-loads; FIFO empty now) ----
    f32x4 accB[2][4];
    #pragma unroll
    for (int m = 0; m < 2; ++m)
        #pragma unroll
        for (int n = 0; n < 4; ++n) accB[m][n] = (f32x4)0.0f;
    #pragma unroll
    for (int kc = 0; kc < 4; ++kc) {
        int kk = kc * 32 + g4 * 8;
        short8 a0 = *(const short8*)&Xbuf[swz(32 * wr + t16,      kk, 128)];
        short8 a1 = *(const short8*)&Xbuf[swz(32 * wr + 16 + t16, kk, 128)];
        #pragma unroll
        for (int n = 0; n < 4; ++n) {
            short8 bmat = *(const short8*)(wsW + WOFF_AM + ((size_t)((4 * wc + n) * 4 + kc)) * 512 + lane * 8);
            accB[0][n] = __builtin_amdgcn_mfma_f32_16x16x32_bf16(a0, bmat, accB[0][n], 0, 0, 0);
            accB[1][n] = __builtin_amdgcn_mfma_f32_16x16x32_bf16(a1, bmat, accB[1][n], 0, 0, 0);
        }
    }
    lds_sync();                                        // all ax reads done

    // stash gate bf16 into own Xbuf cells
    #pragma unroll
    for (int n = 0; n < 4; ++n) {
        int c = 64 * wc + 16 * n + t16;
        float bias = am_b[c];
        #pragma unroll
        for (int m = 0; m < 2; ++m)
            #pragma unroll
            for (int r = 0; r < 4; ++r) {
                int row = 32 * wr + 16 * m + 4 * g4 + r;
                Xbuf[swz(row, c, 128)] = f2bf(sigmoidf_(accB[m][n][r] + bias));
            }
    }
    // no barrier: gate cells are thread-private

    // ---- ffeat = relu(vo1 + vfc_b) * (1 + gate) -> Xbuf ----
    #pragma unroll
    for (int n = 0; n < 4; ++n) {
        int c = 64 * wc + 16 * n + t16;
        float vb = vfc_b[c];
        #pragma unroll
        for (int m = 0; m < 2; ++m)
            #pragma unroll
            for (int r = 0; r < 4; ++r) {
                int row = 32 * wr + 16 * m + 4 * g4 + r;
                float g   = bf2f(Xbuf[swz(row, c, 128)]);
                float vo1 = fmaxf(accC[m][n][r] + vb, 0.0f);
                Xbuf[swz(row, c, 128)] = f2bf(vo1 * (1.0f + g));
            }
    }
    lds_sync();                                        // ffeat visible

    // ---- v/u heads: n=0,1 -> V tiles 2wc+n; n=2,3 -> U tiles 2wc+(n-2) ----
    #pragma unroll
    for (int m = 0; m < 2; ++m)
        #pragma unroll
        for (int n = 0; n < 4; ++n) accB[m][n] = (f32x4)0.0f;
    {
        const ushort* Vp = wsW + WOFF_V;
        const ushort* Up = wsW + WOFF_U;
        #pragma unroll
        for (int kc = 0; kc < 4; ++kc) {
            int kk = kc * 32 + g4 * 8;
            short8 a0 = *(const short8*)&Xbuf[swz(32 * wr + t16,      kk, 128)];
            short8 a1 = *(const short8*)&Xbuf[swz(32 * wr + 16 + t16, kk, 128)];
            #pragma unroll
            for (int n = 0; n < 2; ++n) {
                short8 bv = *(const short8*)(Vp + ((size_t)(2 * wc + n) * 4 + kc) * 512 + lane * 8);
                short8 bu = *(const short8*)(Up + ((size_t)(2 * wc + n) * 4 + kc) * 512 + lane * 8);
                accB[0][n]     = __builtin_amdgcn_mfma_f32_16x16x32_bf16(a0, bv, accB[0][n],     0, 0, 0);
                accB[1][n]     = __builtin_amdgcn_mfma_f32_16x16x32_bf16(a1, bv, accB[1][n],     0, 0, 0);
                accB[0][n + 2] = __builtin_amdgcn_mfma_f32_16x16x32_bf16(a0, bu, accB[0][n + 2], 0, 0, 0);
                accB[1][n + 2] = __builtin_amdgcn_mfma_f32_16x16x32_bf16(a1, bu, accB[1][n + 2], 0, 0, 0);
            }
        }
    }

    // ---- score s = sum_h relu(v)*sigmoid(u)*W_w + W_b ----
    #pragma unroll
    for (int m = 0; m < 2; ++m)
        #pragma unroll
        for (int r = 0; r < 4; ++r) {
            float p = 0.0f;
            #pragma unroll
            for (int n = 0; n < 2; ++n) {
                int h = 32 * wc + 16 * n + t16;
                float vv = fmaxf(accB[m][n][r] + V_b[h], 0.0f);
                float uu = sigmoidf_(accB[m][n + 2][r] + U_b[h]);
                p = fmaf(vv * uu, W_w[h], p);
            }
            p += __shfl_xor(p, 1);
            p += __shfl_xor(p, 2);
            p += __shfl_xor(p, 4);
            p += __shfl_xor(p, 8);
            if (t16 == 0) sPb[wc * 128 + 32 * wr + 16 * m + 4 * g4 + r] = p;
        }
    __syncthreads();
    if (tid < 128) {
        float s = sPb[tid] + sPb[128 + tid] + W_b[0];
        sSb[tid] = s;
        s_out[(size_t)b * N_ + tok0 + tid] = s;
    }
    __syncthreads();

    // ---- zpart[k] = sum_t s[t] * ffeat[t][k] ----
    {
        int k = tid & 127, q = tid >> 7;
        float z = 0.0f;
        #pragma unroll
        for (int t = 0; t < 32; ++t) {
            int row = q * 32 + t;
            z = fmaf(sSb[row], bf2f(Xbuf[swz(row, k, 128)]), z);
        }
        zqb[q * 128 + k] = z;
    }
    __syncthreads();
    if (tid < 128)
        zpart[(size_t)bx * 128 + tid] = zqb[tid] + zqb[128 + tid] + zqb[256 + tid] + zqb[384 + tid];

    #undef ABUF
    #undef BBUF
}

// Grid: 32 blocks, 128 threads.
__global__ __launch_bounds__(128)
void reduce_logits(const float* __restrict__ zpart,
                   const float* __restrict__ cls_w, const float* __restrict__ cls_b,
                   float* __restrict__ out)
{
    __shared__ float sZ[128];
    int b = blockIdx.x, k = threadIdx.x;
    float z = 0.0f;
    #pragma unroll
    for (int t = 0; t < 16; ++t) z += zpart[(size_t)(b * 16 + t) * 128 + k];
    sZ[k] = z;
    __syncthreads();
    if (k < 2) {
        float acc = cls_b[k];
        for (int i = 0; i < 128; ++i) acc = fmaf(sZ[i], cls_w[k * 128 + i], acc);
        out[(size_t)B_ * N_ + b * 2 + k] = acc;
    }
}

extern "C" void kernel_launch(void* const* d_in, const int* in_sizes, int n_in,
                              void* d_out, int out_size, void* d_ws, size_t ws_size,
                              hipStream_t stream) {
    const float* vfeat = (const float*)d_in[0];
    const float* afeat = (const float*)d_in[1];
    const float* vfc_w = (const float*)d_in[2];
    const float* vfc_b = (const float*)d_in[3];
    const float* afc_w = (const float*)d_in[4];
    const float* afc_b = (const float*)d_in[5];
    const float* am_w  = (const float*)d_in[6];
    const float* am_b  = (const float*)d_in[7];
    const float* U_w   = (const float*)d_in[8];
    const float* U_b   = (const float*)d_in[9];
    const float* V_w   = (const float*)d_in[10];
    const float* V_b   = (const float*)d_in[11];
    const float* W_w   = (const float*)d_in[12];
    const float* W_b   = (const float*)d_in[13];
    const float* cls_w = (const float*)d_in[14];
    const float* cls_b = (const float*)d_in[15];

    float* out   = (float*)d_out;
    ushort* wsW  = (ushort*)d_ws;                            // 229376 B packed bf16 weights
    float* zpart = (float*)((char*)d_ws + (size_t)WTOT * 2); // 512*128*4 = 256 KB

    cvt_weights<<<dim3((WTOT / 8 + 255) / 256), dim3(256), 0, stream>>>(vfc_w, afc_w, am_w, V_w, U_w, wsW);
    fused_mil<<<dim3(B_ * 16), dim3(THREADS), 0, stream>>>(
        vfeat, afeat, wsW, afc_b, am_b, vfc_b, V_b, U_b, W_w, W_b, out, zpart);
    reduce_logits<<<dim3(B_), dim3(128), 0, stream>>>(zpart, cls_w, cls_b, out);
}